// Round 1
// baseline (6044.902 us; speedup 1.0000x reference)
//
#include <hip/hip_runtime.h>

// CGIterator: N=50000 nodes, K=128, I=4 chained CG iterations, fp32.
// Fully fused: one block = 4 nodes through all 4 iterations.
// feats live in registers (thread owns (node,k), all 9 m);
// channel-mixing steps go through LDS (thread owns column p).

#define NNODES 50000
#define KCH 128          // K
#define PCH 256          // 2K
#define NITER 4
#define NB 4             // nodes per block

__global__ __launch_bounds__(256, 2)
void cg_fused(const float* __restrict__ f0,
              const float* __restrict__ f1,
              const float* __restrict__ f2,
              const float* __restrict__ Uin,
              const float* __restrict__ gamma,
              const float* __restrict__ W_in,
              const float* __restrict__ W_out,
              float* __restrict__ out)
{
    // symmetrized U, upper triangle a<=b packed: sUp[ab][c], c padded to 12 for b128
    __shared__ float sUp[45][12];
    __shared__ float s_h[NB][9][KCH];    // RMS-normed feats
    __shared__ float s_hc[NB][9][PCH];   // hc, overwritten in place by tp

    const int tid = threadIdx.x;
    const int node0 = blockIdx.x * NB;

    // ---- build symmetrized padded U in LDS (once per block)
    for (int idx = tid; idx < 45 * 12; idx += 256) {
        const int ab = idx / 12;
        const int c  = idx % 12;
        int a = 0, r = ab;
        while (r >= 9 - a) { r -= 9 - a; ++a; }
        const int b = a + r;
        float v = 0.0f;
        if (c < 9) {
            v = Uin[(a * 9 + b) * 9 + c];
            if (a != b) v += Uin[(b * 9 + a) * 9 + c];
        }
        sUp[ab][c] = v;
    }

    const int kk = tid & (KCH - 1);  // channel 0..127
    const int nh = tid >> 7;         // node-half: 0 or 1
    const int p  = tid;              // expanded channel column 0..255

    const int MS[3] = {0, 1, 4};
    const int MC[3] = {1, 3, 5};

    // ---- load initial feats: thread owns nodes 2*nh+{0,1}, channel kk, all m
    float f[2][9];
    #pragma unroll
    for (int j = 0; j < 2; ++j) {
        const int n = node0 + 2 * nh + j;
        f[j][0] = f0[n * KCH + kk];
        #pragma unroll
        for (int m = 0; m < 3; ++m) f[j][1 + m] = f1[(n * 3 + m) * KCH + kk];
        #pragma unroll
        for (int m = 0; m < 5; ++m) f[j][4 + m] = f2[(n * 5 + m) * KCH + kk];
    }

    for (int it = 0; it < NITER; ++it) {
        // ---------- step 1: equivariant RMS norm -> s_h ----------
        const float g0 = gamma[(it * 3 + 0) * KCH + kk];
        const float g1 = gamma[(it * 3 + 1) * KCH + kk];
        const float g2 = gamma[(it * 3 + 2) * KCH + kk];
        #pragma unroll
        for (int j = 0; j < 2; ++j) {
            const int nl = 2 * nh + j;
            const float s0 = f[j][0] * f[j][0];
            const float s1 = f[j][1] * f[j][1] + f[j][2] * f[j][2] + f[j][3] * f[j][3];
            const float s2 = f[j][4] * f[j][4] + f[j][5] * f[j][5] + f[j][6] * f[j][6]
                           + f[j][7] * f[j][7] + f[j][8] * f[j][8];
            const float r0 = rsqrtf(s0 + 1e-6f) * g0;
            const float r1 = rsqrtf(s1 * (1.0f / 3.0f) + 1e-6f) * g1;
            const float r2 = rsqrtf(s2 * (1.0f / 5.0f) + 1e-6f) * g2;
            s_h[nl][0][kk] = f[j][0] * r0;
            s_h[nl][1][kk] = f[j][1] * r1;
            s_h[nl][2][kk] = f[j][2] * r1;
            s_h[nl][3][kk] = f[j][3] * r1;
            s_h[nl][4][kk] = f[j][4] * r2;
            s_h[nl][5][kk] = f[j][5] * r2;
            s_h[nl][6][kk] = f[j][6] * r2;
            s_h[nl][7][kk] = f[j][7] * r2;
            s_h[nl][8][kk] = f[j][8] * r2;
        }
        __syncthreads();   // also protects previous iter's s_hc readers before overwrite

        // ---------- step 2: linear_in  s_hc[n][m][p] = sum_k s_h[n][m][k] * W_in[it,l][k][p]
        #pragma unroll
        for (int l = 0; l < 3; ++l) {
            const float* Wl = W_in + (size_t)(it * 3 + l) * KCH * PCH;
            float acc[NB][5];
            #pragma unroll
            for (int n = 0; n < NB; ++n)
                #pragma unroll
                for (int mm = 0; mm < 5; ++mm) acc[n][mm] = 0.0f;

            #pragma unroll 2
            for (int k = 0; k < KCH; k += 4) {
                const float w0 = Wl[(k + 0) * PCH + p];
                const float w1 = Wl[(k + 1) * PCH + p];
                const float w2 = Wl[(k + 2) * PCH + p];
                const float w3 = Wl[(k + 3) * PCH + p];
                #pragma unroll
                for (int n = 0; n < NB; ++n) {
                    #pragma unroll
                    for (int mm = 0; mm < MC[l]; ++mm) {
                        const float4 h4 = *(const float4*)&s_h[n][MS[l] + mm][k];
                        float a = acc[n][mm];
                        a = fmaf(h4.x, w0, a);
                        a = fmaf(h4.y, w1, a);
                        a = fmaf(h4.z, w2, a);
                        a = fmaf(h4.w, w3, a);
                        acc[n][mm] = a;
                    }
                }
            }
            #pragma unroll
            for (int n = 0; n < NB; ++n)
                #pragma unroll
                for (int mm = 0; mm < MC[l]; ++mm)
                    s_hc[n][MS[l] + mm][p] = acc[n][mm];
        }
        __syncthreads();

        // ---------- step 3: channel-wise CG tensor product (in place, own column p)
        {
            float v[NB][9];
            #pragma unroll
            for (int n = 0; n < NB; ++n)
                #pragma unroll
                for (int a = 0; a < 9; ++a) v[n][a] = s_hc[n][a][p];

            float acc[NB][9];
            #pragma unroll
            for (int n = 0; n < NB; ++n)
                #pragma unroll
                for (int c = 0; c < 9; ++c) acc[n][c] = 0.0f;

            int ab = 0;
            #pragma unroll
            for (int a = 0; a < 9; ++a) {
                #pragma unroll
                for (int b = a; b < 9; ++b) {
                    const float q0 = v[0][a] * v[0][b];
                    const float q1 = v[1][a] * v[1][b];
                    const float q2 = v[2][a] * v[2][b];
                    const float q3 = v[3][a] * v[3][b];
                    const float4 u0 = *(const float4*)&sUp[ab][0];
                    const float4 u1 = *(const float4*)&sUp[ab][4];
                    const float  u8 = sUp[ab][8];
                    const float uu[9] = {u0.x, u0.y, u0.z, u0.w, u1.x, u1.y, u1.z, u1.w, u8};
                    #pragma unroll
                    for (int c = 0; c < 9; ++c) {
                        acc[0][c] = fmaf(uu[c], q0, acc[0][c]);
                        acc[1][c] = fmaf(uu[c], q1, acc[1][c]);
                        acc[2][c] = fmaf(uu[c], q2, acc[2][c]);
                        acc[3][c] = fmaf(uu[c], q3, acc[3][c]);
                    }
                    ++ab;
                }
            }
            #pragma unroll
            for (int n = 0; n < NB; ++n)
                #pragma unroll
                for (int c = 0; c < 9; ++c) s_hc[n][c][p] = acc[n][c];
        }
        __syncthreads();

        // ---------- step 4: linear_out + skip  f[n][m][kk] += sum_p tp[n][m][p]*W_out[it,l][p][kk]
        #pragma unroll
        for (int l = 0; l < 3; ++l) {
            const float* Wl = W_out + (size_t)(it * 3 + l) * PCH * KCH;
            float acc[2][5];
            #pragma unroll
            for (int j = 0; j < 2; ++j)
                #pragma unroll
                for (int mm = 0; mm < 5; ++mm) acc[j][mm] = 0.0f;

            #pragma unroll 2
            for (int pp = 0; pp < PCH; pp += 4) {
                const float w0 = Wl[(pp + 0) * KCH + kk];
                const float w1 = Wl[(pp + 1) * KCH + kk];
                const float w2 = Wl[(pp + 2) * KCH + kk];
                const float w3 = Wl[(pp + 3) * KCH + kk];
                #pragma unroll
                for (int j = 0; j < 2; ++j) {
                    const int nl = 2 * nh + j;
                    #pragma unroll
                    for (int mm = 0; mm < MC[l]; ++mm) {
                        const float4 t4 = *(const float4*)&s_hc[nl][MS[l] + mm][pp];
                        float a = acc[j][mm];
                        a = fmaf(t4.x, w0, a);
                        a = fmaf(t4.y, w1, a);
                        a = fmaf(t4.z, w2, a);
                        a = fmaf(t4.w, w3, a);
                        acc[j][mm] = a;
                    }
                }
            }
            #pragma unroll
            for (int j = 0; j < 2; ++j)
                #pragma unroll
                for (int mm = 0; mm < MC[l]; ++mm)
                    f[j][MS[l] + mm] += acc[j][mm];
        }
        // next iteration's RMS writes s_h (disjoint buffer); the barrier after
        // RMS orders this iteration's s_hc reads before next linear_in writes.
    }

    // ---------- store packed output (N, 9, K)
    #pragma unroll
    for (int j = 0; j < 2; ++j) {
        const int n = node0 + 2 * nh + j;
        #pragma unroll
        for (int m = 0; m < 9; ++m)
            out[(size_t)(n * 9 + m) * KCH + kk] = f[j][m];
    }
}

extern "C" void kernel_launch(void* const* d_in, const int* in_sizes, int n_in,
                              void* d_out, int out_size, void* d_ws, size_t ws_size,
                              hipStream_t stream) {
    const float* f0    = (const float*)d_in[0];
    const float* f1    = (const float*)d_in[1];
    const float* f2    = (const float*)d_in[2];
    const float* U     = (const float*)d_in[3];
    const float* gamma = (const float*)d_in[4];
    const float* W_in  = (const float*)d_in[5];
    const float* W_out = (const float*)d_in[6];
    float* out = (float*)d_out;

    dim3 grid(NNODES / NB);   // 50000 / 4 = 12500, exact
    dim3 block(256);
    hipLaunchKernelGGL(cg_fused, grid, block, 0, stream,
                       f0, f1, f2, U, gamma, W_in, W_out, out);
}